// Round 16
// baseline (452.730 us; speedup 1.0000x reference)
//
#include <hip/hip_runtime.h>
#include <math.h>

#define NN   50000
#define NE   800000
#define NET  850000      // edges + self loops
#define NG   64
#define KIN  500
#define NEG  0.2f

typedef unsigned short ushort_t;
typedef __attribute__((ext_vector_type(8))) short bf8_t;      // 8 bf16 in 4 VGPRs
typedef __attribute__((ext_vector_type(8))) unsigned short us8_t;
typedef __attribute__((ext_vector_type(4))) float f4_t;
typedef __attribute__((ext_vector_type(2))) float f2_t;
typedef __attribute__((ext_vector_type(4))) unsigned u4_t;
typedef __attribute__((ext_vector_type(2))) unsigned u2_t;

__device__ __forceinline__ float bf2f(ushort_t u) {
    unsigned v = ((unsigned)u) << 16;
    return __builtin_bit_cast(float, v);
}
__device__ __forceinline__ ushort_t f2bf(float f) {
    unsigned b = __builtin_bit_cast(unsigned, f);
    unsigned r = (b + 0x7FFFu + ((b >> 16) & 1u)) >> 16;   // RNE
    return (ushort_t)r;
}

// ---------------- fp8 e4m3 (OCP) encode/decode ----------------
#if __has_builtin(__builtin_amdgcn_cvt_f32_fp8)
#define FP8DEC(w, b) __builtin_amdgcn_cvt_f32_fp8((w), (b))
#else
__device__ __forceinline__ float fp8_sw_dec(unsigned w, int b) {
    unsigned by = (w >> (8 * b)) & 0xFFu;
    unsigned s = by >> 7, e = (by >> 3) & 15u, m = by & 7u;
    float v = e ? __builtin_bit_cast(float, ((e + 120u) << 23) | (m << 20))
                : (float)m * 0.001953125f;                 // m * 2^-9
    return s ? -v : v;
}
#define FP8DEC(w, b) fp8_sw_dec((w), (b))
#endif

// packed: 2 fp8 -> 2 f32 in one v_cvt_pk_f32_fp8 (sel=false: bytes 0,1; true: 2,3)
#if __has_builtin(__builtin_amdgcn_cvt_pk_f32_fp8)
__device__ __forceinline__ f2_t fp8_pk_lo(unsigned w) {
    return __builtin_amdgcn_cvt_pk_f32_fp8(w, false);
}
__device__ __forceinline__ f2_t fp8_pk_hi(unsigned w) {
    return __builtin_amdgcn_cvt_pk_f32_fp8(w, true);
}
#else
__device__ __forceinline__ f2_t fp8_pk_lo(unsigned w) {
    f2_t r; r.x = FP8DEC(w, 0); r.y = FP8DEC(w, 1); return r;
}
__device__ __forceinline__ f2_t fp8_pk_hi(unsigned w) {
    f2_t r; r.x = FP8DEC(w, 2); r.y = FP8DEC(w, 3); return r;
}
#endif

#if __has_builtin(__builtin_amdgcn_cvt_pk_fp8_f32)
__device__ __forceinline__ unsigned char f2fp8(float f) {
    return (unsigned char)(__builtin_amdgcn_cvt_pk_fp8_f32(f, 0.f, 0u, false) & 0xFFu);
}
#else
__device__ __forceinline__ unsigned char f2fp8(float f) {
    unsigned u = __builtin_bit_cast(unsigned, f);
    unsigned sgn = (u >> 24) & 0x80u;
    float a = fabsf(f);
    if (!(a < 448.f)) return (unsigned char)(sgn | 0x7Eu);
    if (a < 0.015625f) {                                   // subnormal, step 2^-9
        int m = (int)(a * 512.f + 0.5f);
        return (unsigned char)(sgn | (m > 7 ? 8 : m));
    }
    unsigned r = u + 0x7FFFFu + ((u >> 20) & 1u);          // RNE at 3-bit mantissa
    unsigned e = (r >> 23) & 0xFFu;
    unsigned m = (r >> 20) & 7u;
    if (e > 135u) return (unsigned char)(sgn | 0x7Eu);
    return (unsigned char)(sgn | ((e - 120u) << 3) | m);
}
#endif

#define GLOAD_LDS(g, l)                                                        \
    __builtin_amdgcn_global_load_lds(                                          \
        (const __attribute__((address_space(1))) unsigned int*)(g),            \
        (__attribute__((address_space(3))) unsigned int*)(l), 16, 0, 0)

// ---------------- CSR build (by dst) ----------------
__global__ void k_deg(const int* __restrict__ ei, int* __restrict__ deg) {
    int e = blockIdx.x * 256 + threadIdx.x;
    if (e >= NET) return;
    int dst = (e < NE) ? ei[NE + e] : (e - NE);
    atomicAdd(&deg[dst], 1);
}

__global__ void k_scan_part(const int* __restrict__ deg, int* __restrict__ part) {
    __shared__ int s[256];
    int t = threadIdx.x;
    int i = blockIdx.x * 256 + t;
    s[t] = (i < NN) ? deg[i] : 0;
    __syncthreads();
    for (int off = 128; off > 0; off >>= 1) {
        if (t < off) s[t] += s[t + off];
        __syncthreads();
    }
    if (t == 0) part[blockIdx.x] = s[0];
}

__global__ void k_scan_top(int* __restrict__ part, int nb) {
    __shared__ int s[256];
    int t = threadIdx.x;
    int v = (t < nb) ? part[t] : 0;
    s[t] = v;
    __syncthreads();
    for (int off = 1; off < 256; off <<= 1) {
        int a = (t >= off) ? s[t - off] : 0;
        __syncthreads();
        s[t] += a;
        __syncthreads();
    }
    if (t < nb) part[t] = s[t] - v;   // exclusive
}

__global__ void k_scan_apply(const int* __restrict__ deg, const int* __restrict__ part,
                             int* __restrict__ rowptr) {
    __shared__ int s[256];
    int t = threadIdx.x;
    int i = blockIdx.x * 256 + t;
    int v = (i < NN) ? deg[i] : 0;
    s[t] = v;
    __syncthreads();
    for (int off = 1; off < 256; off <<= 1) {
        int a = (t >= off) ? s[t - off] : 0;
        __syncthreads();
        s[t] += a;
        __syncthreads();
    }
    if (i < NN) rowptr[i] = part[blockIdx.x] + s[t] - v;
    if (i == 0) rowptr[NN] = NET;
}

__global__ void k_fill(const int* __restrict__ ei, const int* __restrict__ rowptr,
                       int* __restrict__ cursor, int* __restrict__ csr) {
    int e = blockIdx.x * 256 + threadIdx.x;
    if (e >= NET) return;
    int src, dst;
    if (e < NE) { src = ei[e]; dst = ei[NE + e]; }
    else        { src = dst = e - NE; }
    int pos = atomicAdd(&cursor[dst], 1);
    csr[rowptr[dst] + pos] = src;
}

// ---------------- bf16 weight cast ----------------
template <int KSRC, int KPAD, int NOUT>
__global__ void k_cast_wt(const float* __restrict__ W, ushort_t* __restrict__ Wt) {
    int idx = blockIdx.x * 256 + threadIdx.x;     // over NOUT*KPAD
    if (idx >= NOUT * KPAD) return;
    int n = idx / KPAD, k = idx - n * KPAD;
    float v = (k < KSRC) ? W[(size_t)k * NOUT + n] : 0.f;
    Wt[idx] = f2bf(v);
}

// ---------------- layer-1 fused GEMM: H1 = bf16(x) @ W1, cast fused ----------
// R7-PROVEN GEOMETRY: BM=128, BN=128, 256 threads = 4 waves (2m x 2n),
// grid dim3(2, 391) = 782 blocks. A staged f32->bf16 in regs (2 slots/thread,
// identical RNE numerics); second column-block's A re-read hits L3 (x = 100MB
// < 256MB L3). B via global_load_lds. LDS 16 KB, narrower barrier groups
// than the 512-thread single-column variant (74 us; R7's shape was <=58).
__global__ __launch_bounds__(256) void k_mfma1f(
    const float* __restrict__ x, const ushort_t* __restrict__ Wt,
    const float* __restrict__ a_s, const float* __restrict__ a_d,
    unsigned char* __restrict__ Hb, float* __restrict__ als, float* __restrict__ ald)
{
    __shared__ __align__(16) ushort_t lA[128 * 32];
    __shared__ __align__(16) ushort_t lB[128 * 32];
    const int t    = threadIdx.x;
    const int row0 = blockIdx.y * 128;
    const int n0   = blockIdx.x * 128;
    const int ww   = t >> 6, lane = t & 63;
    const int wm   = ww & 1, wn = ww >> 1;        // 2 x 2 waves
    const int lrow = lane & 15, lq = lane >> 4;   // quad

    // A staging: 2 slots/thread; slot c = i*256+t covers row (c>>2), kq (c&3)
    const int ar0 = (t >> 2);           // slot 0 row (i=0)
    const int ar1 = (256 + t) >> 2;     // slot 1 row (i=1) = 64 + (t>>2)
    const int akq = t & 3;
    const bool aok0 = (row0 + ar0) < NN;
    const bool aok1 = (row0 + ar1) < NN;
    const float* xr0 = x + (size_t)(row0 + ar0) * KIN;
    const float* xr1 = x + (size_t)(row0 + ar1) * KIN;

    f4_t acc[4][4] = {};

    for (int k0 = 0; k0 < 512; k0 += 32) {
        int kk = k0 + akq * 8;
        // ---- A: global f32 -> regs -> bf16 -> LDS (two b128 writes/thread) ----
        float4 a00 = make_float4(0.f, 0.f, 0.f, 0.f), a01 = a00;
        float4 a10 = a00, a11 = a00;
        if (kk + 4 <= KIN) {
            if (aok0) a00 = *(const float4*)(xr0 + kk);
            if (aok1) a10 = *(const float4*)(xr1 + kk);
            if (kk + 8 <= KIN) {
                if (aok0) a01 = *(const float4*)(xr0 + kk + 4);
                if (aok1) a11 = *(const float4*)(xr1 + kk + 4);
            }
        }
        // ---- B: 128 cols x 32 k via global_load_lds, 2 passes ----
#pragma unroll
        for (int i = 0; i < 2; i++) {
            int c = i * 256 + t;
            int row = c >> 2, kq = c & 3;
            GLOAD_LDS(Wt + (size_t)(n0 + row) * 512 + k0 + kq * 8, &lB[c * 8]);
        }
        us8_t ab0, ab1;
        ab0[0] = f2bf(a00.x); ab0[1] = f2bf(a00.y); ab0[2] = f2bf(a00.z); ab0[3] = f2bf(a00.w);
        ab0[4] = f2bf(a01.x); ab0[5] = f2bf(a01.y); ab0[6] = f2bf(a01.z); ab0[7] = f2bf(a01.w);
        ab1[0] = f2bf(a10.x); ab1[1] = f2bf(a10.y); ab1[2] = f2bf(a10.z); ab1[3] = f2bf(a10.w);
        ab1[4] = f2bf(a11.x); ab1[5] = f2bf(a11.y); ab1[6] = f2bf(a11.z); ab1[7] = f2bf(a11.w);
        *(us8_t*)&lA[ar0 * 32 + akq * 8] = ab0;
        *(us8_t*)&lA[ar1 * 32 + akq * 8] = ab1;
        __syncthreads();
        bf8_t af[4], bfr[4];
#pragma unroll
        for (int i = 0; i < 4; i++)
            af[i] = *(const bf8_t*)&lA[(wm * 64 + i * 16 + lrow) * 32 + lq * 8];
#pragma unroll
        for (int j = 0; j < 4; j++)
            bfr[j] = *(const bf8_t*)&lB[(wn * 64 + j * 16 + lrow) * 32 + lq * 8];
#pragma unroll
        for (int i = 0; i < 4; i++)
#pragma unroll
            for (int j = 0; j < 4; j++)
                acc[i][j] = __builtin_amdgcn_mfma_f32_16x16x32_bf16(af[i], bfr[j], acc[i][j], 0, 0, 0);
        __syncthreads();
    }

    // epilogue: wave's 64 cols = exactly one head (64-wide, 64-aligned)
    const int head = (n0 + wn * 64) >> 6;
    float as4[4], ad4[4];
#pragma unroll
    for (int j = 0; j < 4; j++) {
        as4[j] = a_s[head * 64 + j * 16 + lrow];
        ad4[j] = a_d[head * 64 + j * 16 + lrow];
    }
#pragma unroll
    for (int i = 0; i < 4; i++) {
#pragma unroll
        for (int r = 0; r < 4; r++) {
            int row = row0 + wm * 64 + i * 16 + lq * 4 + r;
            float v0 = acc[i][0][r], v1 = acc[i][1][r], v2 = acc[i][2][r], v3 = acc[i][3][r];
            if (row < NN) {
                size_t base = (size_t)row * 256 + n0 + wn * 64 + lrow;
                Hb[base +  0] = f2fp8(v0);
                Hb[base + 16] = f2fp8(v1);
                Hb[base + 32] = f2fp8(v2);
                Hb[base + 48] = f2fp8(v3);
            }
            float ps = v0 * as4[0] + v1 * as4[1] + v2 * as4[2] + v3 * as4[3];
            float pd = v0 * ad4[0] + v1 * ad4[1] + v2 * ad4[2] + v3 * ad4[3];
#pragma unroll
            for (int off = 1; off < 16; off <<= 1) {
                ps += __shfl_xor(ps, off);
                pd += __shfl_xor(pd, off);
            }
            if (lrow == 0 && row < NN) {
                als[(size_t)row * 4 + head] = ps;
                ald[(size_t)row * 4 + head] = pd;
            }
        }
    }
}

// ---------------- bf16 MFMA GEMM (layer 2): H = A @ W, fused logit epilogue ----
template <int K, int LDA, int BM, int BN, int WM, int FOUT, int HEADS>
__global__ __launch_bounds__(256) void k_mfma(
    const ushort_t* __restrict__ A, const ushort_t* __restrict__ Wt,
    const float* __restrict__ a_s, const float* __restrict__ a_d,
    unsigned char* __restrict__ Hb, float* __restrict__ als, float* __restrict__ ald)
{
    __shared__ __align__(16) ushort_t lA[BM * 32];
    __shared__ __align__(16) ushort_t lB[BN * 32];
    const int t    = threadIdx.x;
    const int row0 = blockIdx.y * BM;
    const int n0   = blockIdx.x * BN;
    const int ww   = t >> 6, lane = t & 63;
    const int wm   = ww % WM, wn = ww / WM;
    const int lrow = lane & 15, lq = lane >> 4;   // quad

    f4_t acc[4][4] = {};

    for (int k0 = 0; k0 < K; k0 += 32) {
#pragma unroll
        for (int i = 0; i < BM / 64; i++) {       // A tile: BM rows x 32 k
            int c = i * 256 + t;
            int row = c >> 2, kq = c & 3;
            const ushort_t* gp = A + (size_t)(row0 + row) * LDA + k0 + kq * 8;
            GLOAD_LDS(gp, &lA[c * 8]);
        }
#pragma unroll
        for (int i = 0; i < BN / 64; i++) {       // B tile: BN cols x 32 k
            int c = i * 256 + t;
            int row = c >> 2, kq = c & 3;
            const ushort_t* gp = Wt + (size_t)(n0 + row) * K + k0 + kq * 8;
            GLOAD_LDS(gp, &lB[c * 8]);
        }
        __syncthreads();
        bf8_t af[4], bfr[4];
#pragma unroll
        for (int i = 0; i < 4; i++)
            af[i] = *(const bf8_t*)&lA[(wm * 64 + i * 16 + lrow) * 32 + lq * 8];
#pragma unroll
        for (int j = 0; j < 4; j++)
            bfr[j] = *(const bf8_t*)&lB[(wn * 64 + j * 16 + lrow) * 32 + lq * 8];
#pragma unroll
        for (int i = 0; i < 4; i++)
#pragma unroll
            for (int j = 0; j < 4; j++)
                acc[i][j] = __builtin_amdgcn_mfma_f32_16x16x32_bf16(af[i], bfr[j], acc[i][j], 0, 0, 0);
        __syncthreads();
    }

    // epilogue: wave's 64 cols = exactly one head (64-wide, 64-aligned)
    const int head = (n0 + wn * 64) >> 6;
    float as4[4], ad4[4];
#pragma unroll
    for (int j = 0; j < 4; j++) {
        as4[j] = a_s[head * 64 + j * 16 + lrow];
        ad4[j] = a_d[head * 64 + j * 16 + lrow];
    }
#pragma unroll
    for (int i = 0; i < 4; i++) {
#pragma unroll
        for (int r = 0; r < 4; r++) {
            int row = row0 + wm * 64 + i * 16 + lq * 4 + r;
            float v0 = acc[i][0][r], v1 = acc[i][1][r], v2 = acc[i][2][r], v3 = acc[i][3][r];
            if (row < NN) {
                size_t base = (size_t)row * FOUT + n0 + wn * 64 + lrow;
                Hb[base +  0] = f2fp8(v0);
                Hb[base + 16] = f2fp8(v1);
                Hb[base + 32] = f2fp8(v2);
                Hb[base + 48] = f2fp8(v3);
            }
            float ps = v0 * as4[0] + v1 * as4[1] + v2 * as4[2] + v3 * as4[3];
            float pd = v0 * ad4[0] + v1 * ad4[1] + v2 * ad4[2] + v3 * ad4[3];
#pragma unroll
            for (int off = 1; off < 16; off <<= 1) {
                ps += __shfl_xor(ps, off);
                pd += __shfl_xor(pd, off);
            }
            if (lrow == 0 && row < NN) {
                als[(size_t)row * HEADS + head] = ps;
                ald[(size_t)row * HEADS + head] = pd;
            }
        }
    }
}

// ---- layer-1 aggregation, two-phase, fp8 gather, packed decode ----
#define CAP1 128
__global__ __launch_bounds__(256) void k_agg1(
    const int* __restrict__ rowptr, const int* __restrict__ csr,
    const unsigned char* __restrict__ Hb, const float* __restrict__ als,
    const float* __restrict__ ald, const float* __restrict__ bias,
    ushort_t* __restrict__ OutB)
{
    __shared__ float salpha[4][CAP1 * 4];
    int w = threadIdx.x >> 6, lane = threadIdx.x & 63;
    int dst = blockIdx.x * 4 + w;
    if (dst >= NN) return;
    float* Aw = salpha[w];
    const int beg = rowptr[dst], end = rowptr[dst + 1];
    const int deg = end - beg;

    const int hd    = lane & 3;
    const int slot  = lane >> 2;
    const int slot2 = lane >> 4;
    const int head2 = (lane >> 2) & 3;
    const int f0    = (lane & 3) * 16;

    // iteration-0 prefetch: issued before phase 1, latency hidden under it
    int  ke    = slot2;
    bool valid = ke < deg;
    int  src   = csr[beg + (valid ? ke : 0)];
    u4_t xv    = *(const u4_t*)&Hb[(size_t)src * 256 + head2 * 64 + f0];

    // ---- phase 1: softmax stats + logit stash ----
    const float adst = ald[dst * 4 + hd];
    float m = -1e30f, s = 0.f;
    for (int k = slot; k < deg; k += 16) {
        int sk = csr[beg + k];
        float e = als[sk * 4 + hd] + adst;
        e = (e > 0.f) ? e : NEG * e;                  // leaky_relu
        if (k < CAP1) Aw[k * 4 + hd] = e;
        float mn = fmaxf(m, e);
        s = s * __expf(m - mn) + __expf(e - mn);
        m = mn;
    }
#pragma unroll
    for (int off = 4; off < 64; off <<= 1) {          // merge 16 slots, keep heads
        float mo = __shfl_xor(m, off);
        float so = __shfl_xor(s, off);
        float mn = fmaxf(m, mo);
        s = s * __expf(m - mn) + so * __expf(mo - mn);
        m = mn;
    }
    float inv = 1.f / (s + 1e-16f);
    int cap4 = (deg < CAP1 ? deg : CAP1) * 4;
    for (int j = lane; j < cap4; j += 64)             // j&3 == lane&3
        Aw[j] = __expf(Aw[j] - m) * inv;

    // ---- phase 2: alpha-weighted fp8 gather, 4 edges/iter, packed math ----
    const float m2  = __shfl(m, head2);               // for the rare deg>CAP1 path
    const float i2  = __shfl(inv, head2);
    const float ad2 = __shfl(adst, head2);

    f2_t facc2[8] = {};                               // 16 f32 as 8 packed pairs
    int k0 = 0;
    while (true) {
        int k0n = k0 + 4;
        bool more = k0n < deg;
        int srcn = 0; u4_t xvn = {}; bool validn = false;
        if (more) {                                   // depth-1 prefetch
            int ken = k0n + slot2;
            validn = ken < deg;
            srcn = csr[beg + (validn ? ken : 0)];
            xvn  = *(const u4_t*)&Hb[(size_t)srcn * 256 + head2 * 64 + f0];
        }
        float al = 0.f;
        if (valid) {
            if (ke < CAP1) {
                al = Aw[ke * 4 + head2];
            } else {                                  // deg > CAP1 fallback (rare)
                float e = als[src * 4 + head2] + ad2;
                e = (e > 0.f) ? e : NEG * e;
                al = __expf(e - m2) * i2;
            }
        }
        f2_t al2; al2.x = al; al2.y = al;
#pragma unroll
        for (int wd = 0; wd < 4; wd++) {
            unsigned wv = xv[wd];
            facc2[wd * 2 + 0] += al2 * fp8_pk_lo(wv);
            facc2[wd * 2 + 1] += al2 * fp8_pk_hi(wv);
        }
        if (!more) break;
        k0 = k0n; ke = k0 + slot2; valid = validn; src = srcn; xv = xvn;
    }
    float facc[16];
#pragma unroll
    for (int j = 0; j < 8; j++) { facc[j * 2] = facc2[j].x; facc[j * 2 + 1] = facc2[j].y; }
#pragma unroll
    for (int j = 0; j < 16; j++) {
        facc[j] += __shfl_xor(facc[j], 16);
        facc[j] += __shfl_xor(facc[j], 32);
    }
    if (lane < 16) {
        us8_t oa, ob;
#pragma unroll
        for (int j = 0; j < 8; j++) {
            float o  = facc[j]     + bias[head2 * 64 + f0 + j];
            float o2 = facc[8 + j] + bias[head2 * 64 + f0 + 8 + j];
            oa[j] = f2bf(o  > 0.f ? o  : 0.f);        // relu
            ob[j] = f2bf(o2 > 0.f ? o2 : 0.f);
        }
        *(us8_t*)&OutB[(size_t)dst * 256 + head2 * 64 + f0]     = oa;
        *(us8_t*)&OutB[(size_t)dst * 256 + head2 * 64 + f0 + 8] = ob;
    }
}

// ---- layer-2 aggregation, two-phase, fp8 gather, packed decode (1 head) ----
#define CAP2 128
__global__ __launch_bounds__(256) void k_agg2(
    const int* __restrict__ rowptr, const int* __restrict__ csr,
    const unsigned char* __restrict__ Hb, const float* __restrict__ als,
    const float* __restrict__ ald, const float* __restrict__ bias,
    float* __restrict__ OutF)
{
    __shared__ float salpha2[4][CAP2];
    int w = threadIdx.x >> 6, lane = threadIdx.x & 63;
    int dst = blockIdx.x * 4 + w;
    if (dst >= NN) return;
    float* Aw = salpha2[w];
    const int beg = rowptr[dst], end = rowptr[dst + 1];
    const int deg = end - beg;
    const float adst = ald[dst];

    const int slot2 = lane >> 3;
    const int f0    = (lane & 7) * 8;

    // iteration-0 prefetch
    int  ke    = slot2;
    bool valid = ke < deg;
    int  src   = csr[beg + (valid ? ke : 0)];
    u2_t xv    = *(const u2_t*)&Hb[(size_t)src * 64 + f0];

    // ---- phase 1 ----
    float m = -1e30f, s = 0.f;
    for (int k = lane; k < deg; k += 64) {
        int sk = csr[beg + k];
        float e = als[sk] + adst;
        e = (e > 0.f) ? e : NEG * e;
        if (k < CAP2) Aw[k] = e;
        float mn = fmaxf(m, e);
        s = s * __expf(m - mn) + __expf(e - mn);
        m = mn;
    }
#pragma unroll
    for (int off = 1; off < 64; off <<= 1) {
        float mo = __shfl_xor(m, off);
        float so = __shfl_xor(s, off);
        float mn = fmaxf(m, mo);
        s = s * __expf(m - mn) + so * __expf(mo - mn);
        m = mn;
    }
    float inv = 1.f / (s + 1e-16f);                   // m, inv now wave-uniform
    int cap = deg < CAP2 ? deg : CAP2;
    for (int j = lane; j < cap; j += 64)
        Aw[j] = __expf(Aw[j] - m) * inv;

    // ---- phase 2: 8 edges/iter fp8 gather, packed math ----
    f2_t facc2[4] = {};
    int k0 = 0;
    while (true) {
        int k0n = k0 + 8;
        bool more = k0n < deg;
        int srcn = 0; u2_t xvn = {}; bool validn = false;
        if (more) {
            int ken = k0n + slot2;
            validn = ken < deg;
            srcn = csr[beg + (validn ? ken : 0)];
            xvn  = *(const u2_t*)&Hb[(size_t)srcn * 64 + f0];
        }
        float al = 0.f;
        if (valid) {
            if (ke < CAP2) {
                al = Aw[ke];
            } else {
                float e = als[src] + adst;
                e = (e > 0.f) ? e : NEG * e;
                al = __expf(e - m) * inv;
            }
        }
        f2_t al2; al2.x = al; al2.y = al;
#pragma unroll
        for (int wd = 0; wd < 2; wd++) {
            unsigned wv = xv[wd];
            facc2[wd * 2 + 0] += al2 * fp8_pk_lo(wv);
            facc2[wd * 2 + 1] += al2 * fp8_pk_hi(wv);
        }
        if (!more) break;
        k0 = k0n; ke = k0 + slot2; valid = validn; src = srcn; xv = xvn;
    }
    float facc[8];
#pragma unroll
    for (int j = 0; j < 4; j++) { facc[j * 2] = facc2[j].x; facc[j * 2 + 1] = facc2[j].y; }
#pragma unroll
    for (int j = 0; j < 8; j++) {
        facc[j] += __shfl_xor(facc[j], 8);
        facc[j] += __shfl_xor(facc[j], 16);
        facc[j] += __shfl_xor(facc[j], 32);
    }
    if (lane < 8) {
        float4 oa, ob;
        float* pa = &oa.x; float* pb = &ob.x;
#pragma unroll
        for (int j = 0; j < 4; j++) {
            float v  = facc[j]     + bias[f0 + j];
            float v2 = facc[4 + j] + bias[f0 + 4 + j];
            pa[j] = (v  > 0.f) ? v  : 0.f;
            pb[j] = (v2 > 0.f) ? v2 : 0.f;
        }
        *(float4*)&OutF[(size_t)dst * 64 + f0]     = oa;
        *(float4*)&OutF[(size_t)dst * 64 + f0 + 4] = ob;
    }
}

// ---------------- parallel mean-pool: stage A (partial sums) ----------------
#define PSPLIT 8
__global__ __launch_bounds__(256) void k_pool_part(
    const float* __restrict__ out2, const int* __restrict__ batch,
    float* __restrict__ pooled)
{
    int g = blockIdx.x >> 3, sp = blockIdx.x & 7;
    int lo, hi;
    { int a = 0, b = NN; while (a < b) { int mm = (a + b) >> 1; if (batch[mm] < g) a = mm + 1; else b = mm; } lo = a; }
    { int a = lo, b = NN; while (a < b) { int mm = (a + b) >> 1; if (batch[mm] < g + 1) a = mm + 1; else b = mm; } hi = a; }
    int t = threadIdx.x, c = t & 63, r = t >> 6;
    float s = 0.f;
    for (int n = lo + sp * 4 + r; n < hi; n += 32)
        s += out2[(size_t)n * 64 + c];
    __shared__ float red[256];
    red[t] = s;
    __syncthreads();
    if (t < 64) {
        float p = red[t] + red[t + 64] + red[t + 128] + red[t + 192];
        atomicAdd(&pooled[g * 64 + t], p);
    }
}

// ---------------- stage B: mean + classifier ----------------
__global__ void k_final(const float* __restrict__ pooled, const int* __restrict__ batch,
                        const float* __restrict__ Wl, const float* __restrict__ bl,
                        float* __restrict__ out)
{
    int g = blockIdx.x;
    int lo, hi;
    { int a = 0, b = NN; while (a < b) { int mm = (a + b) >> 1; if (batch[mm] < g) a = mm + 1; else b = mm; } lo = a; }
    { int a = lo, b = NN; while (a < b) { int mm = (a + b) >> 1; if (batch[mm] < g + 1) a = mm + 1; else b = mm; } hi = a; }
    int t = threadIdx.x;          // 64 threads = 1 wave
    int cnt = hi - lo;
    float p = pooled[g * 64 + t] / (float)(cnt > 0 ? cnt : 1);
    float r0 = p * Wl[t * 2 + 0];
    float r1 = p * Wl[t * 2 + 1];
#pragma unroll
    for (int off = 32; off > 0; off >>= 1) {
        r0 += __shfl_xor(r0, off);
        r1 += __shfl_xor(r1, off);
    }
    if (t == 0) {
        out[g * 2 + 0] = r0 + bl[0];
        out[g * 2 + 1] = r1 + bl[1];
    }
}

extern "C" void kernel_launch(void* const* d_in, const int* in_sizes, int n_in,
                              void* d_out, int out_size, void* d_ws, size_t ws_size,
                              hipStream_t stream)
{
    const float* x    = (const float*)d_in[0];
    const int*   ei   = (const int*)  d_in[1];
    const int*   batch= (const int*)  d_in[2];
    const float* W1   = (const float*)d_in[3];
    const float* as1  = (const float*)d_in[4];
    const float* ad1  = (const float*)d_in[5];
    const float* b1   = (const float*)d_in[6];
    const float* W2   = (const float*)d_in[7];
    const float* as2  = (const float*)d_in[8];
    const float* ad2  = (const float*)d_in[9];
    const float* b2   = (const float*)d_in[10];
    const float* Wl   = (const float*)d_in[11];
    const float* bl   = (const float*)d_in[12];
    float* out = (float*)d_out;

    // ---- workspace carve-up (xb region kept as scratch for out1b/h2b8/out2) ----
    int*   deg    = (int*)d_ws;                       // 50048
    int*   cursor = deg + 50048;                      // 50048
    int*   part   = cursor + 50048;                   // 256
    int*   rowptr = part + 256;                       // 50064
    int*   csr    = rowptr + 50064;                   // 850048
    ushort_t* xb  = (ushort_t*)(csr + 850048);        // 50048*512 scratch
    ushort_t* Wt1 = xb + (size_t)50048 * 512;         // 256*512
    ushort_t* Wt2 = Wt1 + 131072;                     // 64*256
    ushort_t* h1b = Wt2 + 16384;                      // region: 50000*256 ushorts
    unsigned char* h1b8 = (unsigned char*)h1b;        // fp8 table uses 50000*256 B
    float* al1s   = (float*)(h1b + (size_t)50000 * 256); // 200000
    float* al1d   = al1s + 200000;
    float* al2s   = al1d + 200000;                    // 50000
    float* al2d   = al2s + 50000;
    float* pooled = al2d + 50000;                     // 64*64 floats
    // aliases inside xb:
    ushort_t* out1b = xb;                             // 50176*256
    unsigned char* h2b8 = (unsigned char*)(xb + 13000000); // 50000*64 B
    float*    out2  = (float*)(xb + 16400000);        // 50000*64 floats

    hipMemsetAsync(deg, 0, 2 * 50048 * sizeof(int), stream);   // deg + cursor
    hipMemsetAsync(pooled, 0, NG * 64 * sizeof(float), stream);

    // CSR build
    k_deg       <<<(NET + 255) / 256, 256, 0, stream>>>(ei, deg);
    k_scan_part <<<196, 256, 0, stream>>>(deg, part);
    k_scan_top  <<<1,   256, 0, stream>>>(part, 196);
    k_scan_apply<<<196, 256, 0, stream>>>(deg, part, rowptr);
    k_fill      <<<(NET + 255) / 256, 256, 0, stream>>>(ei, rowptr, cursor, csr);

    // weight casts (bf16, zero-padded K)
    k_cast_wt<500, 512, 256><<<(256 * 512 + 255) / 256, 256, 0, stream>>>(W1, Wt1);
    k_cast_wt<256, 256, 64> <<<(64 * 256 + 255) / 256, 256, 0, stream>>>(W2, Wt2);

    // layer 1: fused cast + GEMM, M=50048(pad), BM=128, BN=128, dim3(2,391)
    k_mfma1f<<<dim3(2, 391), 256, 0, stream>>>(x, Wt1, as1, ad1, h1b8, al1s, al1d);
    k_agg1<<<(NN + 3) / 4, 256, 0, stream>>>(rowptr, csr, h1b8, al1s, al1d, b1, out1b);
    // zero pad rows 50000..50175 of out1b for GEMM2
    hipMemsetAsync(out1b + (size_t)50000 * 256, 0, (size_t)176 * 256 * sizeof(ushort_t), stream);

    // layer 2: M=50176(pad), N=64, K=256; tile 256x64, 4x1 waves
    k_mfma<256, 256, 256, 64, 4, 64, 1><<<dim3(1, 196), 256, 0, stream>>>(
        out1b, Wt2, as2, ad2, h2b8, al2s, al2d);
    k_agg2<<<(NN + 3) / 4, 256, 0, stream>>>(rowptr, csr, h2b8, al2s, al2d, b2, out2);

    // parallel mean-pool + classifier
    k_pool_part<<<NG * PSPLIT, 256, 0, stream>>>(out2, batch, pooled);
    k_final    <<<NG, 64, 0, stream>>>(pooled, batch, Wl, bl, out);
}

// Round 17
// 418.766 us; speedup vs baseline: 1.0811x; 1.0811x over previous
//
#include <hip/hip_runtime.h>
#include <math.h>

#define NN   50000
#define NE   800000
#define NET  850000      // edges + self loops
#define NG   64
#define KIN  500
#define NEG  0.2f

typedef unsigned short ushort_t;
typedef __attribute__((ext_vector_type(8))) short bf8_t;      // 8 bf16 in 4 VGPRs
typedef __attribute__((ext_vector_type(8))) unsigned short us8_t;
typedef __attribute__((ext_vector_type(4))) float f4_t;
typedef __attribute__((ext_vector_type(2))) float f2_t;
typedef __attribute__((ext_vector_type(4))) unsigned u4_t;
typedef __attribute__((ext_vector_type(2))) unsigned u2_t;

__device__ __forceinline__ float bf2f(ushort_t u) {
    unsigned v = ((unsigned)u) << 16;
    return __builtin_bit_cast(float, v);
}
__device__ __forceinline__ ushort_t f2bf(float f) {
    unsigned b = __builtin_bit_cast(unsigned, f);
    unsigned r = (b + 0x7FFFu + ((b >> 16) & 1u)) >> 16;   // RNE
    return (ushort_t)r;
}

// ---------------- fp8 e4m3 (OCP) encode/decode ----------------
#if __has_builtin(__builtin_amdgcn_cvt_f32_fp8)
#define FP8DEC(w, b) __builtin_amdgcn_cvt_f32_fp8((w), (b))
#else
__device__ __forceinline__ float fp8_sw_dec(unsigned w, int b) {
    unsigned by = (w >> (8 * b)) & 0xFFu;
    unsigned s = by >> 7, e = (by >> 3) & 15u, m = by & 7u;
    float v = e ? __builtin_bit_cast(float, ((e + 120u) << 23) | (m << 20))
                : (float)m * 0.001953125f;                 // m * 2^-9
    return s ? -v : v;
}
#define FP8DEC(w, b) fp8_sw_dec((w), (b))
#endif

// packed: 2 fp8 -> 2 f32 in one v_cvt_pk_f32_fp8 (sel=false: bytes 0,1; true: 2,3)
#if __has_builtin(__builtin_amdgcn_cvt_pk_f32_fp8)
__device__ __forceinline__ f2_t fp8_pk_lo(unsigned w) {
    return __builtin_amdgcn_cvt_pk_f32_fp8(w, false);
}
__device__ __forceinline__ f2_t fp8_pk_hi(unsigned w) {
    return __builtin_amdgcn_cvt_pk_f32_fp8(w, true);
}
#else
__device__ __forceinline__ f2_t fp8_pk_lo(unsigned w) {
    f2_t r; r.x = FP8DEC(w, 0); r.y = FP8DEC(w, 1); return r;
}
__device__ __forceinline__ f2_t fp8_pk_hi(unsigned w) {
    f2_t r; r.x = FP8DEC(w, 2); r.y = FP8DEC(w, 3); return r;
}
#endif

#if __has_builtin(__builtin_amdgcn_cvt_pk_fp8_f32)
__device__ __forceinline__ unsigned char f2fp8(float f) {
    return (unsigned char)(__builtin_amdgcn_cvt_pk_fp8_f32(f, 0.f, 0u, false) & 0xFFu);
}
#else
__device__ __forceinline__ unsigned char f2fp8(float f) {
    unsigned u = __builtin_bit_cast(unsigned, f);
    unsigned sgn = (u >> 24) & 0x80u;
    float a = fabsf(f);
    if (!(a < 448.f)) return (unsigned char)(sgn | 0x7Eu);
    if (a < 0.015625f) {                                   // subnormal, step 2^-9
        int m = (int)(a * 512.f + 0.5f);
        return (unsigned char)(sgn | (m > 7 ? 8 : m));
    }
    unsigned r = u + 0x7FFFFu + ((u >> 20) & 1u);          // RNE at 3-bit mantissa
    unsigned e = (r >> 23) & 0xFFu;
    unsigned m = (r >> 20) & 7u;
    if (e > 135u) return (unsigned char)(sgn | 0x7Eu);
    return (unsigned char)(sgn | ((e - 120u) << 3) | m);
}
#endif

#define GLOAD_LDS(g, l)                                                        \
    __builtin_amdgcn_global_load_lds(                                          \
        (const __attribute__((address_space(1))) unsigned int*)(g),            \
        (__attribute__((address_space(3))) unsigned int*)(l), 16, 0, 0)

// ---------------- CSR build (by dst) ----------------
__global__ void k_deg(const int* __restrict__ ei, int* __restrict__ deg) {
    int e = blockIdx.x * 256 + threadIdx.x;
    if (e >= NET) return;
    int dst = (e < NE) ? ei[NE + e] : (e - NE);
    atomicAdd(&deg[dst], 1);
}

__global__ void k_scan_part(const int* __restrict__ deg, int* __restrict__ part) {
    __shared__ int s[256];
    int t = threadIdx.x;
    int i = blockIdx.x * 256 + t;
    s[t] = (i < NN) ? deg[i] : 0;
    __syncthreads();
    for (int off = 128; off > 0; off >>= 1) {
        if (t < off) s[t] += s[t + off];
        __syncthreads();
    }
    if (t == 0) part[blockIdx.x] = s[0];
}

__global__ void k_scan_top(int* __restrict__ part, int nb) {
    __shared__ int s[256];
    int t = threadIdx.x;
    int v = (t < nb) ? part[t] : 0;
    s[t] = v;
    __syncthreads();
    for (int off = 1; off < 256; off <<= 1) {
        int a = (t >= off) ? s[t - off] : 0;
        __syncthreads();
        s[t] += a;
        __syncthreads();
    }
    if (t < nb) part[t] = s[t] - v;   // exclusive
}

__global__ void k_scan_apply(const int* __restrict__ deg, const int* __restrict__ part,
                             int* __restrict__ rowptr) {
    __shared__ int s[256];
    int t = threadIdx.x;
    int i = blockIdx.x * 256 + t;
    int v = (i < NN) ? deg[i] : 0;
    s[t] = v;
    __syncthreads();
    for (int off = 1; off < 256; off <<= 1) {
        int a = (t >= off) ? s[t - off] : 0;
        __syncthreads();
        s[t] += a;
        __syncthreads();
    }
    if (i < NN) rowptr[i] = part[blockIdx.x] + s[t] - v;
    if (i == 0) rowptr[NN] = NET;
}

__global__ void k_fill(const int* __restrict__ ei, const int* __restrict__ rowptr,
                       int* __restrict__ cursor, int* __restrict__ csr) {
    int e = blockIdx.x * 256 + threadIdx.x;
    if (e >= NET) return;
    int src, dst;
    if (e < NE) { src = ei[e]; dst = ei[NE + e]; }
    else        { src = dst = e - NE; }
    int pos = atomicAdd(&cursor[dst], 1);
    csr[rowptr[dst] + pos] = src;
}

// ---------------- bf16 weight cast ----------------
template <int KSRC, int KPAD, int NOUT>
__global__ void k_cast_wt(const float* __restrict__ W, ushort_t* __restrict__ Wt) {
    int idx = blockIdx.x * 256 + threadIdx.x;     // over NOUT*KPAD
    if (idx >= NOUT * KPAD) return;
    int n = idx / KPAD, k = idx - n * KPAD;
    float v = (k < KSRC) ? W[(size_t)k * NOUT + n] : 0.f;
    Wt[idx] = f2bf(v);
}

// ---------------- layer-1 fused GEMM: H1 = bf16(x) @ W1, cast fused ----------
// BM=128, BN=256 (full N, A read ONCE), 512 threads = 8 waves (2m x 4n).
// FINAL (R8-measured, 71.5 us): best of all fused variants — explicit dbuf
// (R9), BM=64 (R12), and 2-column BM=128/BN=128 (R16, A re-read NOT
// L3-absorbed: FETCH doubled) all regressed. A staged f32->bf16 in registers
// (same RNE as a separate cast -> identical numerics), B via global_load_lds.
__global__ __launch_bounds__(512) void k_mfma1f(
    const float* __restrict__ x, const ushort_t* __restrict__ Wt,
    const float* __restrict__ a_s, const float* __restrict__ a_d,
    unsigned char* __restrict__ Hb, float* __restrict__ als, float* __restrict__ ald)
{
    __shared__ __align__(16) ushort_t lA[128 * 32];
    __shared__ __align__(16) ushort_t lB[256 * 32];
    const int t    = threadIdx.x;
    const int row0 = blockIdx.y * 128;
    const int ww   = t >> 6, lane = t & 63;
    const int wm   = ww & 1, wn = ww >> 1;        // 2 x 4 waves
    const int lrow = lane & 15, lq = lane >> 4;   // quad

    // A staging geometry: slot t covers row (t>>2), k-chunk (t&3)*8 (one pass)
    const int arow  = t >> 2;
    const int akq   = t & 3;
    const int arowg = row0 + arow;
    const bool arok = arowg < NN;
    const float* xrow = x + (size_t)arowg * KIN;

    f4_t acc[4][4] = {};

    for (int k0 = 0; k0 < 512; k0 += 32) {
        // ---- A: global f32 -> regs -> bf16 -> LDS (one b128 write/thread) ----
        int kk = k0 + akq * 8;
        float4 v0 = make_float4(0.f, 0.f, 0.f, 0.f);
        float4 v1 = make_float4(0.f, 0.f, 0.f, 0.f);
        if (arok && kk + 4 <= KIN) {
            v0 = *(const float4*)(xrow + kk);
            if (kk + 8 <= KIN) v1 = *(const float4*)(xrow + kk + 4);
        }
        us8_t ab;
        ab[0] = f2bf(v0.x); ab[1] = f2bf(v0.y); ab[2] = f2bf(v0.z); ab[3] = f2bf(v0.w);
        ab[4] = f2bf(v1.x); ab[5] = f2bf(v1.y); ab[6] = f2bf(v1.z); ab[7] = f2bf(v1.w);
        *(us8_t*)&lA[arow * 32 + akq * 8] = ab;
        // ---- B: 256 cols x 32 k via global_load_lds, 2 passes ----
#pragma unroll
        for (int i = 0; i < 2; i++) {
            int c = i * 512 + t;
            int row = c >> 2, kq = c & 3;
            const ushort_t* gp = Wt + (size_t)row * 512 + k0 + kq * 8;
            GLOAD_LDS(gp, &lB[c * 8]);
        }
        __syncthreads();
        bf8_t af[4], bfr[4];
#pragma unroll
        for (int i = 0; i < 4; i++)
            af[i] = *(const bf8_t*)&lA[(wm * 64 + i * 16 + lrow) * 32 + lq * 8];
#pragma unroll
        for (int j = 0; j < 4; j++)
            bfr[j] = *(const bf8_t*)&lB[(wn * 64 + j * 16 + lrow) * 32 + lq * 8];
#pragma unroll
        for (int i = 0; i < 4; i++)
#pragma unroll
            for (int j = 0; j < 4; j++)
                acc[i][j] = __builtin_amdgcn_mfma_f32_16x16x32_bf16(af[i], bfr[j], acc[i][j], 0, 0, 0);
        __syncthreads();
    }

    // epilogue: wave's 64 cols = head wn
    const int head = wn;
    float as4[4], ad4[4];
#pragma unroll
    for (int j = 0; j < 4; j++) {
        as4[j] = a_s[head * 64 + j * 16 + lrow];
        ad4[j] = a_d[head * 64 + j * 16 + lrow];
    }
#pragma unroll
    for (int i = 0; i < 4; i++) {
#pragma unroll
        for (int r = 0; r < 4; r++) {
            int row = row0 + wm * 64 + i * 16 + lq * 4 + r;
            float v0 = acc[i][0][r], v1 = acc[i][1][r], v2 = acc[i][2][r], v3 = acc[i][3][r];
            if (row < NN) {
                size_t base = (size_t)row * 256 + wn * 64 + lrow;
                Hb[base +  0] = f2fp8(v0);
                Hb[base + 16] = f2fp8(v1);
                Hb[base + 32] = f2fp8(v2);
                Hb[base + 48] = f2fp8(v3);
            }
            float ps = v0 * as4[0] + v1 * as4[1] + v2 * as4[2] + v3 * as4[3];
            float pd = v0 * ad4[0] + v1 * ad4[1] + v2 * ad4[2] + v3 * ad4[3];
#pragma unroll
            for (int off = 1; off < 16; off <<= 1) {
                ps += __shfl_xor(ps, off);
                pd += __shfl_xor(pd, off);
            }
            if (lrow == 0 && row < NN) {
                als[(size_t)row * 4 + head] = ps;
                ald[(size_t)row * 4 + head] = pd;
            }
        }
    }
}

// ---------------- bf16 MFMA GEMM (layer 2): H = A @ W, fused logit epilogue ----
template <int K, int LDA, int BM, int BN, int WM, int FOUT, int HEADS>
__global__ __launch_bounds__(256) void k_mfma(
    const ushort_t* __restrict__ A, const ushort_t* __restrict__ Wt,
    const float* __restrict__ a_s, const float* __restrict__ a_d,
    unsigned char* __restrict__ Hb, float* __restrict__ als, float* __restrict__ ald)
{
    __shared__ __align__(16) ushort_t lA[BM * 32];
    __shared__ __align__(16) ushort_t lB[BN * 32];
    const int t    = threadIdx.x;
    const int row0 = blockIdx.y * BM;
    const int n0   = blockIdx.x * BN;
    const int ww   = t >> 6, lane = t & 63;
    const int wm   = ww % WM, wn = ww / WM;
    const int lrow = lane & 15, lq = lane >> 4;   // quad

    f4_t acc[4][4] = {};

    for (int k0 = 0; k0 < K; k0 += 32) {
#pragma unroll
        for (int i = 0; i < BM / 64; i++) {       // A tile: BM rows x 32 k
            int c = i * 256 + t;
            int row = c >> 2, kq = c & 3;
            const ushort_t* gp = A + (size_t)(row0 + row) * LDA + k0 + kq * 8;
            GLOAD_LDS(gp, &lA[c * 8]);
        }
#pragma unroll
        for (int i = 0; i < BN / 64; i++) {       // B tile: BN cols x 32 k
            int c = i * 256 + t;
            int row = c >> 2, kq = c & 3;
            const ushort_t* gp = Wt + (size_t)(n0 + row) * K + k0 + kq * 8;
            GLOAD_LDS(gp, &lB[c * 8]);
        }
        __syncthreads();
        bf8_t af[4], bfr[4];
#pragma unroll
        for (int i = 0; i < 4; i++)
            af[i] = *(const bf8_t*)&lA[(wm * 64 + i * 16 + lrow) * 32 + lq * 8];
#pragma unroll
        for (int j = 0; j < 4; j++)
            bfr[j] = *(const bf8_t*)&lB[(wn * 64 + j * 16 + lrow) * 32 + lq * 8];
#pragma unroll
        for (int i = 0; i < 4; i++)
#pragma unroll
            for (int j = 0; j < 4; j++)
                acc[i][j] = __builtin_amdgcn_mfma_f32_16x16x32_bf16(af[i], bfr[j], acc[i][j], 0, 0, 0);
        __syncthreads();
    }

    // epilogue: wave's 64 cols = exactly one head (64-wide, 64-aligned)
    const int head = (n0 + wn * 64) >> 6;
    float as4[4], ad4[4];
#pragma unroll
    for (int j = 0; j < 4; j++) {
        as4[j] = a_s[head * 64 + j * 16 + lrow];
        ad4[j] = a_d[head * 64 + j * 16 + lrow];
    }
#pragma unroll
    for (int i = 0; i < 4; i++) {
#pragma unroll
        for (int r = 0; r < 4; r++) {
            int row = row0 + wm * 64 + i * 16 + lq * 4 + r;
            float v0 = acc[i][0][r], v1 = acc[i][1][r], v2 = acc[i][2][r], v3 = acc[i][3][r];
            if (row < NN) {
                size_t base = (size_t)row * FOUT + n0 + wn * 64 + lrow;
                Hb[base +  0] = f2fp8(v0);
                Hb[base + 16] = f2fp8(v1);
                Hb[base + 32] = f2fp8(v2);
                Hb[base + 48] = f2fp8(v3);
            }
            float ps = v0 * as4[0] + v1 * as4[1] + v2 * as4[2] + v3 * as4[3];
            float pd = v0 * ad4[0] + v1 * ad4[1] + v2 * ad4[2] + v3 * ad4[3];
#pragma unroll
            for (int off = 1; off < 16; off <<= 1) {
                ps += __shfl_xor(ps, off);
                pd += __shfl_xor(pd, off);
            }
            if (lrow == 0 && row < NN) {
                als[(size_t)row * HEADS + head] = ps;
                ald[(size_t)row * HEADS + head] = pd;
            }
        }
    }
}

// ---- layer-1 aggregation, two-phase, fp8 gather, packed decode ----
#define CAP1 128
__global__ __launch_bounds__(256) void k_agg1(
    const int* __restrict__ rowptr, const int* __restrict__ csr,
    const unsigned char* __restrict__ Hb, const float* __restrict__ als,
    const float* __restrict__ ald, const float* __restrict__ bias,
    ushort_t* __restrict__ OutB)
{
    __shared__ float salpha[4][CAP1 * 4];
    int w = threadIdx.x >> 6, lane = threadIdx.x & 63;
    int dst = blockIdx.x * 4 + w;
    if (dst >= NN) return;
    float* Aw = salpha[w];
    const int beg = rowptr[dst], end = rowptr[dst + 1];
    const int deg = end - beg;

    const int hd    = lane & 3;
    const int slot  = lane >> 2;
    const int slot2 = lane >> 4;
    const int head2 = (lane >> 2) & 3;
    const int f0    = (lane & 3) * 16;

    // iteration-0 prefetch: issued before phase 1, latency hidden under it
    int  ke    = slot2;
    bool valid = ke < deg;
    int  src   = csr[beg + (valid ? ke : 0)];
    u4_t xv    = *(const u4_t*)&Hb[(size_t)src * 256 + head2 * 64 + f0];

    // ---- phase 1: softmax stats + logit stash ----
    const float adst = ald[dst * 4 + hd];
    float m = -1e30f, s = 0.f;
    for (int k = slot; k < deg; k += 16) {
        int sk = csr[beg + k];
        float e = als[sk * 4 + hd] + adst;
        e = (e > 0.f) ? e : NEG * e;                  // leaky_relu
        if (k < CAP1) Aw[k * 4 + hd] = e;
        float mn = fmaxf(m, e);
        s = s * __expf(m - mn) + __expf(e - mn);
        m = mn;
    }
#pragma unroll
    for (int off = 4; off < 64; off <<= 1) {          // merge 16 slots, keep heads
        float mo = __shfl_xor(m, off);
        float so = __shfl_xor(s, off);
        float mn = fmaxf(m, mo);
        s = s * __expf(m - mn) + so * __expf(mo - mn);
        m = mn;
    }
    float inv = 1.f / (s + 1e-16f);
    int cap4 = (deg < CAP1 ? deg : CAP1) * 4;
    for (int j = lane; j < cap4; j += 64)             // j&3 == lane&3
        Aw[j] = __expf(Aw[j] - m) * inv;

    // ---- phase 2: alpha-weighted fp8 gather, 4 edges/iter, packed math ----
    const float m2  = __shfl(m, head2);               // for the rare deg>CAP1 path
    const float i2  = __shfl(inv, head2);
    const float ad2 = __shfl(adst, head2);

    f2_t facc2[8] = {};                               // 16 f32 as 8 packed pairs
    int k0 = 0;
    while (true) {
        int k0n = k0 + 4;
        bool more = k0n < deg;
        int srcn = 0; u4_t xvn = {}; bool validn = false;
        if (more) {                                   // depth-1 prefetch
            int ken = k0n + slot2;
            validn = ken < deg;
            srcn = csr[beg + (validn ? ken : 0)];
            xvn  = *(const u4_t*)&Hb[(size_t)srcn * 256 + head2 * 64 + f0];
        }
        float al = 0.f;
        if (valid) {
            if (ke < CAP1) {
                al = Aw[ke * 4 + head2];
            } else {                                  // deg > CAP1 fallback (rare)
                float e = als[src * 4 + head2] + ad2;
                e = (e > 0.f) ? e : NEG * e;
                al = __expf(e - m2) * i2;
            }
        }
        f2_t al2; al2.x = al; al2.y = al;
#pragma unroll
        for (int wd = 0; wd < 4; wd++) {
            unsigned wv = xv[wd];
            facc2[wd * 2 + 0] += al2 * fp8_pk_lo(wv);
            facc2[wd * 2 + 1] += al2 * fp8_pk_hi(wv);
        }
        if (!more) break;
        k0 = k0n; ke = k0 + slot2; valid = validn; src = srcn; xv = xvn;
    }
    float facc[16];
#pragma unroll
    for (int j = 0; j < 8; j++) { facc[j * 2] = facc2[j].x; facc[j * 2 + 1] = facc2[j].y; }
#pragma unroll
    for (int j = 0; j < 16; j++) {
        facc[j] += __shfl_xor(facc[j], 16);
        facc[j] += __shfl_xor(facc[j], 32);
    }
    if (lane < 16) {
        us8_t oa, ob;
#pragma unroll
        for (int j = 0; j < 8; j++) {
            float o  = facc[j]     + bias[head2 * 64 + f0 + j];
            float o2 = facc[8 + j] + bias[head2 * 64 + f0 + 8 + j];
            oa[j] = f2bf(o  > 0.f ? o  : 0.f);        // relu
            ob[j] = f2bf(o2 > 0.f ? o2 : 0.f);
        }
        *(us8_t*)&OutB[(size_t)dst * 256 + head2 * 64 + f0]     = oa;
        *(us8_t*)&OutB[(size_t)dst * 256 + head2 * 64 + f0 + 8] = ob;
    }
}

// ---- layer-2 aggregation, two-phase, fp8 gather, packed decode (1 head) ----
#define CAP2 128
__global__ __launch_bounds__(256) void k_agg2(
    const int* __restrict__ rowptr, const int* __restrict__ csr,
    const unsigned char* __restrict__ Hb, const float* __restrict__ als,
    const float* __restrict__ ald, const float* __restrict__ bias,
    float* __restrict__ OutF)
{
    __shared__ float salpha2[4][CAP2];
    int w = threadIdx.x >> 6, lane = threadIdx.x & 63;
    int dst = blockIdx.x * 4 + w;
    if (dst >= NN) return;
    float* Aw = salpha2[w];
    const int beg = rowptr[dst], end = rowptr[dst + 1];
    const int deg = end - beg;
    const float adst = ald[dst];

    const int slot2 = lane >> 3;
    const int f0    = (lane & 7) * 8;

    // iteration-0 prefetch
    int  ke    = slot2;
    bool valid = ke < deg;
    int  src   = csr[beg + (valid ? ke : 0)];
    u2_t xv    = *(const u2_t*)&Hb[(size_t)src * 64 + f0];

    // ---- phase 1 ----
    float m = -1e30f, s = 0.f;
    for (int k = lane; k < deg; k += 64) {
        int sk = csr[beg + k];
        float e = als[sk] + adst;
        e = (e > 0.f) ? e : NEG * e;
        if (k < CAP2) Aw[k] = e;
        float mn = fmaxf(m, e);
        s = s * __expf(m - mn) + __expf(e - mn);
        m = mn;
    }
#pragma unroll
    for (int off = 1; off < 64; off <<= 1) {
        float mo = __shfl_xor(m, off);
        float so = __shfl_xor(s, off);
        float mn = fmaxf(m, mo);
        s = s * __expf(m - mn) + so * __expf(mo - mn);
        m = mn;
    }
    float inv = 1.f / (s + 1e-16f);                   // m, inv now wave-uniform
    int cap = deg < CAP2 ? deg : CAP2;
    for (int j = lane; j < cap; j += 64)
        Aw[j] = __expf(Aw[j] - m) * inv;

    // ---- phase 2: 8 edges/iter fp8 gather, packed math ----
    f2_t facc2[4] = {};
    int k0 = 0;
    while (true) {
        int k0n = k0 + 8;
        bool more = k0n < deg;
        int srcn = 0; u2_t xvn = {}; bool validn = false;
        if (more) {
            int ken = k0n + slot2;
            validn = ken < deg;
            srcn = csr[beg + (validn ? ken : 0)];
            xvn  = *(const u2_t*)&Hb[(size_t)srcn * 64 + f0];
        }
        float al = 0.f;
        if (valid) {
            if (ke < CAP2) {
                al = Aw[ke];
            } else {
                float e = als[src] + adst;
                e = (e > 0.f) ? e : NEG * e;
                al = __expf(e - m) * inv;
            }
        }
        f2_t al2; al2.x = al; al2.y = al;
#pragma unroll
        for (int wd = 0; wd < 2; wd++) {
            unsigned wv = xv[wd];
            facc2[wd * 2 + 0] += al2 * fp8_pk_lo(wv);
            facc2[wd * 2 + 1] += al2 * fp8_pk_hi(wv);
        }
        if (!more) break;
        k0 = k0n; ke = k0 + slot2; valid = validn; src = srcn; xv = xvn;
    }
    float facc[8];
#pragma unroll
    for (int j = 0; j < 4; j++) { facc[j * 2] = facc2[j].x; facc[j * 2 + 1] = facc2[j].y; }
#pragma unroll
    for (int j = 0; j < 8; j++) {
        facc[j] += __shfl_xor(facc[j], 8);
        facc[j] += __shfl_xor(facc[j], 16);
        facc[j] += __shfl_xor(facc[j], 32);
    }
    if (lane < 8) {
        float4 oa, ob;
        float* pa = &oa.x; float* pb = &ob.x;
#pragma unroll
        for (int j = 0; j < 4; j++) {
            float v  = facc[j]     + bias[f0 + j];
            float v2 = facc[4 + j] + bias[f0 + 4 + j];
            pa[j] = (v  > 0.f) ? v  : 0.f;
            pb[j] = (v2 > 0.f) ? v2 : 0.f;
        }
        *(float4*)&OutF[(size_t)dst * 64 + f0]     = oa;
        *(float4*)&OutF[(size_t)dst * 64 + f0 + 4] = ob;
    }
}

// ---------------- parallel mean-pool: stage A (partial sums) ----------------
#define PSPLIT 8
__global__ __launch_bounds__(256) void k_pool_part(
    const float* __restrict__ out2, const int* __restrict__ batch,
    float* __restrict__ pooled)
{
    int g = blockIdx.x >> 3, sp = blockIdx.x & 7;
    int lo, hi;
    { int a = 0, b = NN; while (a < b) { int mm = (a + b) >> 1; if (batch[mm] < g) a = mm + 1; else b = mm; } lo = a; }
    { int a = lo, b = NN; while (a < b) { int mm = (a + b) >> 1; if (batch[mm] < g + 1) a = mm + 1; else b = mm; } hi = a; }
    int t = threadIdx.x, c = t & 63, r = t >> 6;
    float s = 0.f;
    for (int n = lo + sp * 4 + r; n < hi; n += 32)
        s += out2[(size_t)n * 64 + c];
    __shared__ float red[256];
    red[t] = s;
    __syncthreads();
    if (t < 64) {
        float p = red[t] + red[t + 64] + red[t + 128] + red[t + 192];
        atomicAdd(&pooled[g * 64 + t], p);
    }
}

// ---------------- stage B: mean + classifier ----------------
__global__ void k_final(const float* __restrict__ pooled, const int* __restrict__ batch,
                        const float* __restrict__ Wl, const float* __restrict__ bl,
                        float* __restrict__ out)
{
    int g = blockIdx.x;
    int lo, hi;
    { int a = 0, b = NN; while (a < b) { int mm = (a + b) >> 1; if (batch[mm] < g) a = mm + 1; else b = mm; } lo = a; }
    { int a = lo, b = NN; while (a < b) { int mm = (a + b) >> 1; if (batch[mm] < g + 1) a = mm + 1; else b = mm; } hi = a; }
    int t = threadIdx.x;          // 64 threads = 1 wave
    int cnt = hi - lo;
    float p = pooled[g * 64 + t] / (float)(cnt > 0 ? cnt : 1);
    float r0 = p * Wl[t * 2 + 0];
    float r1 = p * Wl[t * 2 + 1];
#pragma unroll
    for (int off = 32; off > 0; off >>= 1) {
        r0 += __shfl_xor(r0, off);
        r1 += __shfl_xor(r1, off);
    }
    if (t == 0) {
        out[g * 2 + 0] = r0 + bl[0];
        out[g * 2 + 1] = r1 + bl[1];
    }
}

extern "C" void kernel_launch(void* const* d_in, const int* in_sizes, int n_in,
                              void* d_out, int out_size, void* d_ws, size_t ws_size,
                              hipStream_t stream)
{
    const float* x    = (const float*)d_in[0];
    const int*   ei   = (const int*)  d_in[1];
    const int*   batch= (const int*)  d_in[2];
    const float* W1   = (const float*)d_in[3];
    const float* as1  = (const float*)d_in[4];
    const float* ad1  = (const float*)d_in[5];
    const float* b1   = (const float*)d_in[6];
    const float* W2   = (const float*)d_in[7];
    const float* as2  = (const float*)d_in[8];
    const float* ad2  = (const float*)d_in[9];
    const float* b2   = (const float*)d_in[10];
    const float* Wl   = (const float*)d_in[11];
    const float* bl   = (const float*)d_in[12];
    float* out = (float*)d_out;

    // ---- workspace carve-up (xb region kept as scratch for out1b/h2b8/out2) ----
    int*   deg    = (int*)d_ws;                       // 50048
    int*   cursor = deg + 50048;                      // 50048
    int*   part   = cursor + 50048;                   // 256
    int*   rowptr = part + 256;                       // 50064
    int*   csr    = rowptr + 50064;                   // 850048
    ushort_t* xb  = (ushort_t*)(csr + 850048);        // 50048*512 scratch
    ushort_t* Wt1 = xb + (size_t)50048 * 512;         // 256*512
    ushort_t* Wt2 = Wt1 + 131072;                     // 64*256
    ushort_t* h1b = Wt2 + 16384;                      // region: 50000*256 ushorts
    unsigned char* h1b8 = (unsigned char*)h1b;        // fp8 table uses 50000*256 B
    float* al1s   = (float*)(h1b + (size_t)50000 * 256); // 200000
    float* al1d   = al1s + 200000;
    float* al2s   = al1d + 200000;                    // 50000
    float* al2d   = al2s + 50000;
    float* pooled = al2d + 50000;                     // 64*64 floats
    // aliases inside xb:
    ushort_t* out1b = xb;                             // 50176*256
    unsigned char* h2b8 = (unsigned char*)(xb + 13000000); // 50000*64 B
    float*    out2  = (float*)(xb + 16400000);        // 50000*64 floats

    hipMemsetAsync(deg, 0, 2 * 50048 * sizeof(int), stream);   // deg + cursor
    hipMemsetAsync(pooled, 0, NG * 64 * sizeof(float), stream);

    // CSR build
    k_deg       <<<(NET + 255) / 256, 256, 0, stream>>>(ei, deg);
    k_scan_part <<<196, 256, 0, stream>>>(deg, part);
    k_scan_top  <<<1,   256, 0, stream>>>(part, 196);
    k_scan_apply<<<196, 256, 0, stream>>>(deg, part, rowptr);
    k_fill      <<<(NET + 255) / 256, 256, 0, stream>>>(ei, rowptr, cursor, csr);

    // weight casts (bf16, zero-padded K)
    k_cast_wt<500, 512, 256><<<(256 * 512 + 255) / 256, 256, 0, stream>>>(W1, Wt1);
    k_cast_wt<256, 256, 64> <<<(64 * 256 + 255) / 256, 256, 0, stream>>>(W2, Wt2);

    // layer 1: fused cast + GEMM, M=50048(pad), N=256 single pass, K=512(pad)
    k_mfma1f<<<dim3(1, 391), 512, 0, stream>>>(x, Wt1, as1, ad1, h1b8, al1s, al1d);
    k_agg1<<<(NN + 3) / 4, 256, 0, stream>>>(rowptr, csr, h1b8, al1s, al1d, b1, out1b);
    // zero pad rows 50000..50175 of out1b for GEMM2
    hipMemsetAsync(out1b + (size_t)50000 * 256, 0, (size_t)176 * 256 * sizeof(ushort_t), stream);

    // layer 2: M=50176(pad), N=64, K=256; tile 256x64, 4x1 waves
    k_mfma<256, 256, 256, 64, 4, 64, 1><<<dim3(1, 196), 256, 0, stream>>>(
        out1b, Wt2, as2, ad2, h2b8, al2s, al2d);
    k_agg2<<<(NN + 3) / 4, 256, 0, stream>>>(rowptr, csr, h2b8, al2s, al2d, b2, out2);

    // parallel mean-pool + classifier
    k_pool_part<<<NG * PSPLIT, 256, 0, stream>>>(out2, batch, pooled);
    k_final    <<<NG, 64, 0, stream>>>(pooled, batch, Wl, bl, out);
}